// Round 4
// baseline (396.323 us; speedup 1.0000x reference)
//
#include <hip/hip_runtime.h>

// B=64 T=1024 D=512 H=512 O=128 HALF=256 ALPHA_M=0.8
// Pipeline:
//   wcast  : w1,w2,wo fp32 -> bf16 (tiny; enables global_load_lds B-staging)
//   gtab   : fix-up tables G1/G2 [16][512] f32
//   gemm1f : tile 64x128, nt-loop inside; A staged via VALU fp32->bf16 pack (fused cast),
//            B via global_load_lds; in-LDS local chunk scan (CLEN=16, swizzled tiles)
//            -> mems bf16 + chunk end-states.  LDS=40KB -> 4 blocks/CU.
//   scanB  : sequential chunk-state combine (NC=64) -> D1/D2/DM prefix states
//   gemm2f : fix-up in VALU A-staging + MFMA + bias + sigmoid -> out fp32

#define B_    64
#define T_    1024
#define D_    512
#define H_    512
#define O_    128
#define HALF_ 256
#define CLEN  16
#define NC    64

typedef __attribute__((ext_vector_type(4))) float        f32x4;
typedef __attribute__((ext_vector_type(2))) float        f32x2;
typedef __attribute__((ext_vector_type(8))) short        s16x8;
typedef __attribute__((ext_vector_type(4))) unsigned int u32x4;

__device__ __forceinline__ unsigned short f2bf(float f) {
    unsigned u = __float_as_uint(f);
    return (unsigned short)((u + 0x7fffu + ((u >> 16) & 1u)) >> 16);  // RNE
}
__device__ __forceinline__ unsigned packbf(float a, float b) {
    return (unsigned)f2bf(a) | ((unsigned)f2bf(b) << 16);
}
__device__ __forceinline__ float bflo(unsigned u) { return __uint_as_float(u << 16); }
__device__ __forceinline__ float bfhi(unsigned u) { return __uint_as_float(u & 0xffff0000u); }
__device__ __forceinline__ float sigf(float x) { return 1.f / (1.f + __expf(-x)); }
__device__ __forceinline__ float guard(float dn) {
    if (fabsf(dn) < 1e-6f) dn = (dn < 0.f ? -1e-6f : 1e-6f);
    return dn;
}
__device__ __forceinline__ float pw16(float a) {  // a^16
    float t = a * a; t *= t; t *= t; t *= t; return t;
}

typedef const __attribute__((address_space(1))) unsigned int gu32;
typedef __attribute__((address_space(3))) unsigned int      lu32;
__device__ __forceinline__ void gl_lds16(const void* g, void* l) {
    __builtin_amdgcn_global_load_lds((gu32*)g, (lu32*)l, 16, 0, 0);
}

// ---------------- wcast: w1|w2|wo fp32 -> contiguous bf16 --------------------------------
__global__ __launch_bounds__(256) void wcast_kernel(
    const float* __restrict__ w1, const float* __restrict__ w2,
    const float* __restrict__ wo, unsigned int* __restrict__ dst)
{
    int g = blockIdx.x * 256 + threadIdx.x;   // 0..40959
    int i = g * 8;
    const float* src; int off;
    if (i < 131072)      { src = w1; off = i; }
    else if (i < 262144) { src = w2; off = i - 131072; }
    else                 { src = wo; off = i - 262144; }
    f32x4 a = *(const f32x4*)(src + off);
    f32x4 b = *(const f32x4*)(src + off + 4);
    u32x4 p;
    p.x = packbf(a.x, a.y); p.y = packbf(a.z, a.w);
    p.z = packbf(b.x, b.y); p.w = packbf(b.z, b.w);
    *(u32x4*)(dst + i / 2) = p;
}

// ---------------- gtab: G1[k][h] = c1(h)*(0.8^{k+1} - a1(h)^{k+1}) -----------------------
__global__ __launch_bounds__(256) void gtab_kernel(
    const float* __restrict__ tau1, const float* __restrict__ tau2,
    float* __restrict__ G1, float* __restrict__ G2)
{
    const int h = blockIdx.x * 256 + threadIdx.x;   // 0..511
    const float a1 = sigf(tau1[h]), a2 = sigf(tau2[h]);
    const float c1 = 0.2f * a1 / guard(0.8f - a1);
    const float c2 = 0.2f * a2 / guard(0.8f - a2);
    float pm = 1.f, p1 = 1.f, p2 = 1.f;
    for (int k = 0; k < CLEN; ++k) {
        pm *= 0.8f; p1 *= a1; p2 *= a2;
        G1[k * H_ + h] = c1 * (pm - p1);
        G2[k * H_ + h] = c2 * (pm - p2);
    }
}

// ---------------- gemm1f: 64x128 tile, nt inside, fused cast + local scan ---------------
__global__ __launch_bounds__(256, 4) void gemm1f_kernel(
    const float* __restrict__ x,
    const unsigned short* __restrict__ w1b, const unsigned short* __restrict__ w2b,
    const float* __restrict__ b1, const float* __restrict__ tau1,
    const float* __restrict__ b2, const float* __restrict__ tau2,
    unsigned int* __restrict__ mems,
    float* __restrict__ Sd1, float* __restrict__ Sd2, float* __restrict__ Sm)
{
    __shared__ short smem[20480];          // 40 KB
    short* As = smem;                      // 4096 shorts (64 x 64, swizzled k-groups)
    short* Bs = smem + 4096;               // 8192 shorts (128 x 64)
    // d2L aliases smem[0..8192); d1L = smem[12288..20480)

    const int mt = blockIdx.x;             // 0..1023
    const int b  = mt >> 4;
    const int tb = mt & 15;
    const int m0 = mt * 64;

    const int tid = threadIdx.x, l = tid & 63, wv = tid >> 6;
    const int ln = l & 15, qd = l >> 4;
    const int wm = (wv & 1) << 5;          // 0/32
    const int wn = (wv >> 1) << 6;         // 0/64

    for (int nt = 0; nt < 4; ++nt) {
        for (int br = 0; br < 2; ++br) {
            const unsigned short* wbase = (br ? w2b : w1b) + (size_t)(nt * 128) * HALF_;
            const float* ab = x + (size_t)m0 * D_ + br * HALF_;

            f32x4 acc[2][4] = {};

            for (int kt = 0; kt < HALF_; kt += 64) {
                // B tile via async DMA (bf16 weights)
                #pragma unroll
                for (int i = 0; i < 4; ++i) {
                    int ch = wv * 4 + i;
                    int r  = ch * 8 + (l >> 3);
                    int kbl = (l & 7) ^ (r & 7);
                    gl_lds16(wbase + (size_t)r * HALF_ + kt + kbl * 8,
                             &Bs[ch * 512 + l * 8]);
                }
                // A tile via VALU pack (this IS the x fp32->bf16 cast)
                #pragma unroll
                for (int i = 0; i < 2; ++i) {
                    int gi = i * 256 + tid;
                    int r = gi >> 3, kbp = gi & 7, kbl = kbp ^ (r & 7);
                    const float* src = ab + (size_t)r * D_ + kt + kbl * 8;
                    f32x4 a0 = *(const f32x4*)src;
                    f32x4 a1v = *(const f32x4*)(src + 4);
                    u32x4 pa;
                    pa.x = packbf(a0.x, a0.y); pa.y = packbf(a0.z, a0.w);
                    pa.z = packbf(a1v.x, a1v.y); pa.w = packbf(a1v.z, a1v.w);
                    *(u32x4*)&As[r * 64 + kbp * 8] = pa;
                }
                __syncthreads();
                #pragma unroll
                for (int ks = 0; ks < 64; ks += 32) {
                    s16x8 af[2], bfv[4];
                    #pragma unroll
                    for (int i = 0; i < 2; ++i) {
                        int r = wm + i * 16 + ln;
                        int kbp = ((ks >> 3) + qd) ^ (r & 7);
                        af[i] = *(const s16x8*)&As[r * 64 + kbp * 8];
                    }
                    #pragma unroll
                    for (int j = 0; j < 4; ++j) {
                        int r = wn + j * 16 + ln;
                        int kbp = ((ks >> 3) + qd) ^ (r & 7);
                        bfv[j] = *(const s16x8*)&Bs[r * 64 + kbp * 8];
                    }
                    #pragma unroll
                    for (int i = 0; i < 2; ++i)
                        #pragma unroll
                        for (int j = 0; j < 4; ++j)
                            acc[i][j] = __builtin_amdgcn_mfma_f32_16x16x32_bf16(
                                af[i], bfv[j], acc[i][j], 0, 0, 0);
                }
                __syncthreads();
            }

            // dump acc -> swizzled d-tile (bank-conflict-free: qd XORs the octet)
            short* dS = br ? smem : (smem + 12288);
            #pragma unroll
            for (int i = 0; i < 2; ++i)
                #pragma unroll
                for (int j = 0; j < 4; ++j)
                    #pragma unroll
                    for (int r = 0; r < 4; ++r) {
                        int t = wm + i * 16 + qd * 4 + r;
                        int h = wn + j * 16 + ln;
                        int word = t * 64 + ((h >> 1) ^ (qd << 3));
                        dS[word * 2 + (h & 1)] = (short)f2bf(acc[i][j][r]);
                    }
        }
        __syncthreads();

        // local chunk scans from LDS: wave = chunk (CLEN=16), lane = h-pair
        const int cl  = tid >> 6;
        const int h2l = tid & 63;
        const int hg0 = nt * 128 + (h2l << 1);
        const int cg  = tb * 4 + cl;

        const float a1a = sigf(tau1[hg0]), a1b = sigf(tau1[hg0 + 1]);
        const float a2a = sigf(tau2[hg0]), a2b = sigf(tau2[hg0 + 1]);
        const float o1a = 1.f - a1a, o1b = 1.f - a1b;
        const float o2a = 1.f - a2a, o2b = 1.f - a2b;
        const float bb1a = b1[hg0], bb1b = b1[hg0 + 1];
        const float bb2a = b2[hg0], bb2b = b2[hg0 + 1];

        const unsigned* d1p = (const unsigned*)(smem + 12288);
        const unsigned* d2p = (const unsigned*)smem;

        float d1a = 0.f, d1b = 0.f, d2a = 0.f, d2b = 0.f, ma = 0.f, mb = 0.f;
        const size_t mrow = ((size_t)(b * T_ + tb * 64 + cl * CLEN)) * (H_ / 2)
                            + nt * 64 + h2l;

        #pragma unroll
        for (int k = 0; k < CLEN; ++k) {
            int tw = (cl * CLEN + k) * 64;
            int sw = h2l ^ (((k >> 2) & 3) << 3);
            unsigned u1 = d1p[tw + sw];
            unsigned u2 = d2p[tw + sw];
            float i1a = bflo(u1) + bb1a, i1b = bfhi(u1) + bb1b;
            float i2a = bflo(u2) + bb2a, i2b = bfhi(u2) + bb2b;
            d1a = a1a * d1a + o1a * i1a;  d1b = a1b * d1b + o1b * i1b;
            d2a = a2a * d2a + o2a * i2a;  d2b = a2b * d2b + o2b * i2b;
            ma = 0.8f * ma + 0.2f * (d1a + d2a);
            mb = 0.8f * mb + 0.2f * (d1b + d2b);
            mems[mrow + (size_t)k * (H_ / 2)] = packbf(ma, mb);
        }

        const size_t si = (size_t)(cg * B_ + b) * H_ + hg0;
        f32x2 v;
        v.x = d1a; v.y = d1b; *(f32x2*)&Sd1[si] = v;
        v.x = d2a; v.y = d2b; *(f32x2*)&Sd2[si] = v;
        v.x = ma;  v.y = mb;  *(f32x2*)&Sm[si]  = v;
        __syncthreads();   // protect d-tiles before next nt restages
    }
}

// ---------------- scanB: sequential chunk-state combine (NC=64) --------------------------
__global__ __launch_bounds__(128) void scanB_kernel(
    const float* __restrict__ Sd1, const float* __restrict__ Sd2,
    const float* __restrict__ Sm,
    const float* __restrict__ tau1, const float* __restrict__ tau2,
    float* __restrict__ D1, float* __restrict__ D2, float* __restrict__ DM)
{
    const int g = blockIdx.x * 128 + threadIdx.x;  // 0..16383
    const int h2 = g & 255, b = g >> 8, h0 = h2 << 1;

    const float a1a = sigf(tau1[h0]), a1b = sigf(tau1[h0 + 1]);
    const float a2a = sigf(tau2[h0]), a2b = sigf(tau2[h0 + 1]);
    const float amL = pw16(0.8f);
    const float a1La = pw16(a1a), a1Lb = pw16(a1b);
    const float a2La = pw16(a2a), a2Lb = pw16(a2b);

    const float c1a = 0.2f * a1a / guard(0.8f - a1a);
    const float c1b = 0.2f * a1b / guard(0.8f - a1b);
    const float c2a = 0.2f * a2a / guard(0.8f - a2a);
    const float c2b = 0.2f * a2b / guard(0.8f - a2b);

    const float g1La = c1a * (amL - a1La), g1Lb = c1b * (amL - a1Lb);
    const float g2La = c2a * (amL - a2La), g2Lb = c2b * (amL - a2Lb);

    float D1a = 0.f, D1b = 0.f, D2a = 0.f, D2b = 0.f, Ma = 0.f, Mb = 0.f;
    for (int c = 0; c < NC; ++c) {
        const size_t si = (size_t)(c * B_ + b) * H_ + h0;
        f32x2 v;
        v.x = D1a; v.y = D1b; *(f32x2*)&D1[si] = v;
        v.x = D2a; v.y = D2b; *(f32x2*)&D2[si] = v;
        v.x = Ma;  v.y = Mb;  *(f32x2*)&DM[si] = v;
        f32x2 s1 = *(const f32x2*)&Sd1[si];
        f32x2 s2 = *(const f32x2*)&Sd2[si];
        f32x2 sm = *(const f32x2*)&Sm[si];
        float nMa = amL * Ma + D1a * g1La + D2a * g2La + sm.x;
        float nMb = amL * Mb + D1b * g1Lb + D2b * g2Lb + sm.y;
        D1a = a1La * D1a + s1.x;  D1b = a1Lb * D1b + s1.y;
        D2a = a2La * D2a + s2.x;  D2b = a2Lb * D2b + s2.y;
        Ma = nMa;  Mb = nMb;
    }
}

// ---------------- gemm2f: fix-up in A-staging + MFMA + bias + sigmoid --------------------
__global__ __launch_bounds__(256, 2) void gemm2f_kernel(
    const unsigned short* __restrict__ mems, const unsigned short* __restrict__ wob,
    const float* __restrict__ bo,
    const float* __restrict__ G1, const float* __restrict__ G2,
    const float* __restrict__ D1, const float* __restrict__ D2,
    const float* __restrict__ DM, float* __restrict__ out)
{
    __shared__ short As[128 * 64];
    __shared__ short Bs[128 * 64];
    __shared__ float PMl[CLEN];

    const int mt = blockIdx.x;
    const int b = mt >> 3, c0 = (mt & 7) << 3;   // 8 chunks of 16 per 128-row tile
    const int tid = threadIdx.x, l = tid & 63, wv = tid >> 6;
    const int ln = l & 15, qd = l >> 4;
    const int wm = (wv & 1) << 6, wn = (wv >> 1) << 6;

    if (tid < CLEN) {
        float pm = 1.f;
        for (int k = 0; k <= tid; ++k) pm *= 0.8f;
        PMl[tid] = pm;                       // 0.8^{k+1}
    }
    __syncthreads();

    f32x4 acc[4][4] = {};
    const unsigned short* abase = mems + (size_t)(mt * 128) * H_;

    for (int kt = 0; kt < H_; kt += 64) {
        // B tile via async DMA (bf16 wo)
        #pragma unroll
        for (int i = 0; i < 4; ++i) {
            int ch = wv * 4 + i;
            int r  = ch * 8 + (l >> 3);
            int kbl = (l & 7) ^ (r & 7);
            gl_lds16(wob + (size_t)r * H_ + kt + kbl * 8, &Bs[ch * 512 + l * 8]);
        }
        // A staging with fix-up (VALU)
        #pragma unroll
        for (int i = 0; i < 4; ++i) {
            int gi = i * 256 + tid;
            int r = gi >> 3, kbp = gi & 7, kbl = kbp ^ (r & 7);
            int h0 = kt + kbl * 8;
            int k = r & (CLEN - 1), c = c0 + (r >> 4);
            size_t dbase = (size_t)(c * B_ + b) * H_ + h0;
            f32x4 d1a = *(const f32x4*)&D1[dbase], d1b = *(const f32x4*)&D1[dbase + 4];
            f32x4 d2a = *(const f32x4*)&D2[dbase], d2b = *(const f32x4*)&D2[dbase + 4];
            f32x4 dma = *(const f32x4*)&DM[dbase], dmb = *(const f32x4*)&DM[dbase + 4];
            f32x4 g1a = *(const f32x4*)&G1[k * H_ + h0], g1b = *(const f32x4*)&G1[k * H_ + h0 + 4];
            f32x4 g2a = *(const f32x4*)&G2[k * H_ + h0], g2b = *(const f32x4*)&G2[k * H_ + h0 + 4];
            float pm = PMl[k];
            u32x4 mv = *(const u32x4*)(abase + (size_t)r * H_ + h0);
            float v0 = bflo(mv.x) + d1a.x * g1a.x + d2a.x * g2a.x + dma.x * pm;
            float v1 = bfhi(mv.x) + d1a.y * g1a.y + d2a.y * g2a.y + dma.y * pm;
            float v2 = bflo(mv.y) + d1a.z * g1a.z + d2a.z * g2a.z + dma.z * pm;
            float v3 = bfhi(mv.y) + d1a.w * g1a.w + d2a.w * g2a.w + dma.w * pm;
            float v4 = bflo(mv.z) + d1b.x * g1b.x + d2b.x * g2b.x + dmb.x * pm;
            float v5 = bfhi(mv.z) + d1b.y * g1b.y + d2b.y * g2b.y + dmb.y * pm;
            float v6 = bflo(mv.w) + d1b.z * g1b.z + d2b.z * g2b.z + dmb.z * pm;
            float v7 = bfhi(mv.w) + d1b.w * g1b.w + d2b.w * g2b.w + dmb.w * pm;
            u32x4 p;
            p.x = packbf(v0, v1); p.y = packbf(v2, v3);
            p.z = packbf(v4, v5); p.w = packbf(v6, v7);
            *(u32x4*)&As[r * 64 + kbp * 8] = p;
        }
        __syncthreads();
        #pragma unroll
        for (int ks = 0; ks < 64; ks += 32) {
            s16x8 af[4], bfv[4];
            #pragma unroll
            for (int i = 0; i < 4; ++i) {
                int r = wm + i * 16 + ln;
                int kbp = ((ks >> 3) + qd) ^ (r & 7);
                af[i] = *(const s16x8*)&As[r * 64 + kbp * 8];
            }
            #pragma unroll
            for (int j = 0; j < 4; ++j) {
                int r = wn + j * 16 + ln;
                int kbp = ((ks >> 3) + qd) ^ (r & 7);
                bfv[j] = *(const s16x8*)&Bs[r * 64 + kbp * 8];
            }
            #pragma unroll
            for (int i = 0; i < 4; ++i)
                #pragma unroll
                for (int j = 0; j < 4; ++j)
                    acc[i][j] = __builtin_amdgcn_mfma_f32_16x16x32_bf16(
                        af[i], bfv[j], acc[i][j], 0, 0, 0);
        }
        __syncthreads();
    }

    float bov[4];
    #pragma unroll
    for (int j = 0; j < 4; ++j) bov[j] = bo[wn + j * 16 + ln];

    float* orow = out + (size_t)(mt * 128 + wm + qd * 4) * O_ + wn + ln;
    #pragma unroll
    for (int i = 0; i < 4; ++i)
        #pragma unroll
        for (int j = 0; j < 4; ++j)
            #pragma unroll
            for (int r = 0; r < 4; ++r) {
                float v = acc[i][j][r] + bov[j];
                orow[(size_t)(i * 16 + r) * O_ + j * 16] = 1.f / (1.f + __expf(-v));
            }
}

extern "C" void kernel_launch(void* const* d_in, const int* in_sizes, int n_in,
                              void* d_out, int out_size, void* d_ws, size_t ws_size,
                              hipStream_t stream) {
    const float* x    = (const float*)d_in[0];
    const float* w1   = (const float*)d_in[1];
    const float* b1   = (const float*)d_in[2];
    const float* tau1 = (const float*)d_in[3];
    const float* w2   = (const float*)d_in[4];
    const float* b2   = (const float*)d_in[5];
    const float* tau2 = (const float*)d_in[6];
    const float* wo   = (const float*)d_in[7];
    const float* bo   = (const float*)d_in[8];
    float* out = (float*)d_out;

    // ws layout (~113 MiB):
    //  [0,64Mi)       mems bf16 [B*T][H]
    //  [64Mi..112Mi)  Sd1,Sd2,Sm,D1,D2,DM  (NC*B*H f32 = 8 MiB each)
    //  then           G1,G2 (16*512 f32 each), w1b/w2b/wob bf16 contiguous
    char* wsp = (char*)d_ws;
    unsigned int* mems = (unsigned int*)wsp;
    float* Sd1 = (float*)(wsp + (size_t)64 * 1024 * 1024);
    const size_t SARR = (size_t)NC * B_ * H_;       // 2M floats
    float* Sd2 = Sd1 + SARR;
    float* Sm  = Sd1 + 2 * SARR;
    float* D1  = Sd1 + 3 * SARR;
    float* D2  = Sd1 + 4 * SARR;
    float* DM  = Sd1 + 5 * SARR;
    float* G1  = Sd1 + 6 * SARR;
    float* G2  = G1 + CLEN * H_;
    unsigned short* w1b = (unsigned short*)(G2 + CLEN * H_);
    unsigned short* w2b = w1b + 131072;
    unsigned short* wob = w2b + 131072;

    wcast_kernel<<<dim3(160), 256, 0, stream>>>(w1, w2, wo, (unsigned int*)w1b);
    gtab_kernel<<<dim3(2), 256, 0, stream>>>(tau1, tau2, G1, G2);
    gemm1f_kernel<<<dim3(1024), 256, 0, stream>>>(x, w1b, w2b, b1, tau1, b2, tau2,
                                                  mems, Sd1, Sd2, Sm);
    scanB_kernel<<<dim3(128), 128, 0, stream>>>(Sd1, Sd2, Sm, tau1, tau2, D1, D2, DM);
    gemm2f_kernel<<<dim3(512), 256, 0, stream>>>((const unsigned short*)mems, wob, bo,
                                                 G1, G2, D1, D2, DM, out);
}

// Round 5
// 377.035 us; speedup vs baseline: 1.0512x; 1.0512x over previous
//
#include <hip/hip_runtime.h>

// B=64 T=1024 D=512 H=512 O=128 HALF=256 ALPHA_M=0.8
// Pipeline:
//   wcast  : w1,w2,wo fp32 -> bf16 (tiny; enables global_load_lds B-staging)
//   gtab   : fix-up tables G1/G2 [16][512] f32
//   gemm1f : tile 64x128, nt-loop inside; nt=0 A-staging casts x fp32->bf16 (writes xb),
//            nt>=1 A-staging re-reads xb via global_load_lds (L3-resident);
//            B via global_load_lds; in-LDS local chunk scan (CLEN=16, swizzled tiles)
//            -> mems bf16 + chunk end-states.  LDS=40KB -> 4 blocks/CU.
//   scanB  : sequential chunk-state combine (NC=64) -> D1/D2/DM prefix states
//   gemm2f : fix-up in VALU A-staging + MFMA + bias + sigmoid -> out fp32

#define B_    64
#define T_    1024
#define D_    512
#define H_    512
#define O_    128
#define HALF_ 256
#define CLEN  16
#define NC    64

typedef __attribute__((ext_vector_type(4))) float        f32x4;
typedef __attribute__((ext_vector_type(2))) float        f32x2;
typedef __attribute__((ext_vector_type(8))) short        s16x8;
typedef __attribute__((ext_vector_type(4))) unsigned int u32x4;

__device__ __forceinline__ unsigned short f2bf(float f) {
    unsigned u = __float_as_uint(f);
    return (unsigned short)((u + 0x7fffu + ((u >> 16) & 1u)) >> 16);  // RNE
}
__device__ __forceinline__ unsigned packbf(float a, float b) {
    return (unsigned)f2bf(a) | ((unsigned)f2bf(b) << 16);
}
__device__ __forceinline__ float bflo(unsigned u) { return __uint_as_float(u << 16); }
__device__ __forceinline__ float bfhi(unsigned u) { return __uint_as_float(u & 0xffff0000u); }
__device__ __forceinline__ float sigf(float x) { return 1.f / (1.f + __expf(-x)); }
__device__ __forceinline__ float guard(float dn) {
    if (fabsf(dn) < 1e-6f) dn = (dn < 0.f ? -1e-6f : 1e-6f);
    return dn;
}
__device__ __forceinline__ float pw16(float a) {  // a^16
    float t = a * a; t *= t; t *= t; t *= t; return t;
}

typedef const __attribute__((address_space(1))) unsigned int gu32;
typedef __attribute__((address_space(3))) unsigned int      lu32;
__device__ __forceinline__ void gl_lds16(const void* g, void* l) {
    __builtin_amdgcn_global_load_lds((gu32*)g, (lu32*)l, 16, 0, 0);
}

// ---------------- wcast: w1|w2|wo fp32 -> contiguous bf16 --------------------------------
__global__ __launch_bounds__(256) void wcast_kernel(
    const float* __restrict__ w1, const float* __restrict__ w2,
    const float* __restrict__ wo, unsigned int* __restrict__ dst)
{
    int g = blockIdx.x * 256 + threadIdx.x;   // 0..40959
    int i = g * 8;
    const float* src; int off;
    if (i < 131072)      { src = w1; off = i; }
    else if (i < 262144) { src = w2; off = i - 131072; }
    else                 { src = wo; off = i - 262144; }
    f32x4 a = *(const f32x4*)(src + off);
    f32x4 b = *(const f32x4*)(src + off + 4);
    u32x4 p;
    p.x = packbf(a.x, a.y); p.y = packbf(a.z, a.w);
    p.z = packbf(b.x, b.y); p.w = packbf(b.z, b.w);
    *(u32x4*)(dst + i / 2) = p;
}

// ---------------- gtab: G1[k][h] = c1(h)*(0.8^{k+1} - a1(h)^{k+1}) -----------------------
__global__ __launch_bounds__(256) void gtab_kernel(
    const float* __restrict__ tau1, const float* __restrict__ tau2,
    float* __restrict__ G1, float* __restrict__ G2)
{
    const int h = blockIdx.x * 256 + threadIdx.x;   // 0..511
    const float a1 = sigf(tau1[h]), a2 = sigf(tau2[h]);
    const float c1 = 0.2f * a1 / guard(0.8f - a1);
    const float c2 = 0.2f * a2 / guard(0.8f - a2);
    float pm = 1.f, p1 = 1.f, p2 = 1.f;
    for (int k = 0; k < CLEN; ++k) {
        pm *= 0.8f; p1 *= a1; p2 *= a2;
        G1[k * H_ + h] = c1 * (pm - p1);
        G2[k * H_ + h] = c2 * (pm - p2);
    }
}

// ---------------- gemm1f: 64x128 tile, nt inside, cast-on-first-nt + local scan ----------
__global__ __launch_bounds__(256, 4) void gemm1f_kernel(
    const float* __restrict__ x, unsigned short* __restrict__ xb,
    const unsigned short* __restrict__ w1b, const unsigned short* __restrict__ w2b,
    const float* __restrict__ b1, const float* __restrict__ tau1,
    const float* __restrict__ b2, const float* __restrict__ tau2,
    unsigned int* __restrict__ mems,
    float* __restrict__ Sd1, float* __restrict__ Sd2, float* __restrict__ Sm)
{
    __shared__ short smem[20480];          // 40 KB
    short* As = smem;                      // 4096 shorts (64 x 64, swizzled k-groups)
    short* Bs = smem + 4096;               // 8192 shorts (128 x 64)
    // d2L aliases smem[0..8192); d1L = smem[12288..20480)

    const int mt = blockIdx.x;             // 0..1023
    const int b  = mt >> 4;
    const int tb = mt & 15;
    const int m0 = mt * 64;

    const int tid = threadIdx.x, l = tid & 63, wv = tid >> 6;
    const int ln = l & 15, qd = l >> 4;
    const int wm = (wv & 1) << 5;          // 0/32
    const int wn = (wv >> 1) << 6;         // 0/64

    for (int nt = 0; nt < 4; ++nt) {
        for (int br = 0; br < 2; ++br) {
            const unsigned short* wbase = (br ? w2b : w1b) + (size_t)(nt * 128) * HALF_;
            const int koff = br * HALF_;

            f32x4 acc[2][4] = {};

            for (int kt = 0; kt < HALF_; kt += 64) {
                // B tile via async DMA (bf16 weights)
                #pragma unroll
                for (int i = 0; i < 4; ++i) {
                    int ch = wv * 4 + i;
                    int r  = ch * 8 + (l >> 3);
                    int kbl = (l & 7) ^ (r & 7);
                    gl_lds16(wbase + (size_t)r * HALF_ + kt + kbl * 8,
                             &Bs[ch * 512 + l * 8]);
                }
                if (nt == 0) {
                    // A tile via VALU pack (fp32->bf16 cast) + write xb for later nts
                    #pragma unroll
                    for (int i = 0; i < 2; ++i) {
                        int gi = i * 256 + tid;
                        int r = gi >> 3, kbp = gi & 7, kbl = kbp ^ (r & 7);
                        size_t goff = (size_t)(m0 + r) * D_ + koff + kt + kbl * 8;
                        f32x4 a0 = *(const f32x4*)(x + goff);
                        f32x4 a1v = *(const f32x4*)(x + goff + 4);
                        u32x4 pa;
                        pa.x = packbf(a0.x, a0.y); pa.y = packbf(a0.z, a0.w);
                        pa.z = packbf(a1v.x, a1v.y); pa.w = packbf(a1v.z, a1v.w);
                        *(u32x4*)&As[r * 64 + kbp * 8] = pa;
                        *(u32x4*)(xb + goff) = pa;
                    }
                } else {
                    // A tile via async DMA from xb (L3-resident, written at nt=0)
                    #pragma unroll
                    for (int i = 0; i < 2; ++i) {
                        int ch = wv * 2 + i;
                        int r  = ch * 8 + (l >> 3);
                        int kbl = (l & 7) ^ (r & 7);
                        gl_lds16(xb + (size_t)(m0 + r) * D_ + koff + kt + kbl * 8,
                                 &As[ch * 512 + l * 8]);
                    }
                }
                __syncthreads();
                #pragma unroll
                for (int ks = 0; ks < 64; ks += 32) {
                    s16x8 af[2], bfv[4];
                    #pragma unroll
                    for (int i = 0; i < 2; ++i) {
                        int r = wm + i * 16 + ln;
                        int kbp = ((ks >> 3) + qd) ^ (r & 7);
                        af[i] = *(const s16x8*)&As[r * 64 + kbp * 8];
                    }
                    #pragma unroll
                    for (int j = 0; j < 4; ++j) {
                        int r = wn + j * 16 + ln;
                        int kbp = ((ks >> 3) + qd) ^ (r & 7);
                        bfv[j] = *(const s16x8*)&Bs[r * 64 + kbp * 8];
                    }
                    #pragma unroll
                    for (int i = 0; i < 2; ++i)
                        #pragma unroll
                        for (int j = 0; j < 4; ++j)
                            acc[i][j] = __builtin_amdgcn_mfma_f32_16x16x32_bf16(
                                af[i], bfv[j], acc[i][j], 0, 0, 0);
                }
                __syncthreads();
            }

            // dump acc -> swizzled d-tile (bank-conflict-free: qd XORs the octet)
            short* dS = br ? smem : (smem + 12288);
            #pragma unroll
            for (int i = 0; i < 2; ++i)
                #pragma unroll
                for (int j = 0; j < 4; ++j)
                    #pragma unroll
                    for (int r = 0; r < 4; ++r) {
                        int t = wm + i * 16 + qd * 4 + r;
                        int h = wn + j * 16 + ln;
                        int word = t * 64 + ((h >> 1) ^ (qd << 3));
                        dS[word * 2 + (h & 1)] = (short)f2bf(acc[i][j][r]);
                    }
        }
        __syncthreads();

        // local chunk scans from LDS: wave = chunk (CLEN=16), lane = h-pair
        const int cl  = tid >> 6;
        const int h2l = tid & 63;
        const int hg0 = nt * 128 + (h2l << 1);
        const int cg  = tb * 4 + cl;

        const float a1a = sigf(tau1[hg0]), a1b = sigf(tau1[hg0 + 1]);
        const float a2a = sigf(tau2[hg0]), a2b = sigf(tau2[hg0 + 1]);
        const float o1a = 1.f - a1a, o1b = 1.f - a1b;
        const float o2a = 1.f - a2a, o2b = 1.f - a2b;
        const float bb1a = b1[hg0], bb1b = b1[hg0 + 1];
        const float bb2a = b2[hg0], bb2b = b2[hg0 + 1];

        const unsigned* d1p = (const unsigned*)(smem + 12288);
        const unsigned* d2p = (const unsigned*)smem;

        float d1a = 0.f, d1b = 0.f, d2a = 0.f, d2b = 0.f, ma = 0.f, mb = 0.f;
        const size_t mrow = ((size_t)(b * T_ + tb * 64 + cl * CLEN)) * (H_ / 2)
                            + nt * 64 + h2l;

        #pragma unroll
        for (int k = 0; k < CLEN; ++k) {
            int tw = (cl * CLEN + k) * 64;
            int sw = h2l ^ (((k >> 2) & 3) << 3);
            unsigned u1 = d1p[tw + sw];
            unsigned u2 = d2p[tw + sw];
            float i1a = bflo(u1) + bb1a, i1b = bfhi(u1) + bb1b;
            float i2a = bflo(u2) + bb2a, i2b = bfhi(u2) + bb2b;
            d1a = a1a * d1a + o1a * i1a;  d1b = a1b * d1b + o1b * i1b;
            d2a = a2a * d2a + o2a * i2a;  d2b = a2b * d2b + o2b * i2b;
            ma = 0.8f * ma + 0.2f * (d1a + d2a);
            mb = 0.8f * mb + 0.2f * (d1b + d2b);
            mems[mrow + (size_t)k * (H_ / 2)] = packbf(ma, mb);
        }

        const size_t si = (size_t)(cg * B_ + b) * H_ + hg0;
        f32x2 v;
        v.x = d1a; v.y = d1b; *(f32x2*)&Sd1[si] = v;
        v.x = d2a; v.y = d2b; *(f32x2*)&Sd2[si] = v;
        v.x = ma;  v.y = mb;  *(f32x2*)&Sm[si]  = v;
        __syncthreads();   // protect d-tiles before next nt restages
    }
}

// ---------------- scanB: sequential chunk-state combine (NC=64) --------------------------
__global__ __launch_bounds__(128) void scanB_kernel(
    const float* __restrict__ Sd1, const float* __restrict__ Sd2,
    const float* __restrict__ Sm,
    const float* __restrict__ tau1, const float* __restrict__ tau2,
    float* __restrict__ D1, float* __restrict__ D2, float* __restrict__ DM)
{
    const int g = blockIdx.x * 128 + threadIdx.x;  // 0..16383
    const int h2 = g & 255, b = g >> 8, h0 = h2 << 1;

    const float a1a = sigf(tau1[h0]), a1b = sigf(tau1[h0 + 1]);
    const float a2a = sigf(tau2[h0]), a2b = sigf(tau2[h0 + 1]);
    const float amL = pw16(0.8f);
    const float a1La = pw16(a1a), a1Lb = pw16(a1b);
    const float a2La = pw16(a2a), a2Lb = pw16(a2b);

    const float c1a = 0.2f * a1a / guard(0.8f - a1a);
    const float c1b = 0.2f * a1b / guard(0.8f - a1b);
    const float c2a = 0.2f * a2a / guard(0.8f - a2a);
    const float c2b = 0.2f * a2b / guard(0.8f - a2b);

    const float g1La = c1a * (amL - a1La), g1Lb = c1b * (amL - a1Lb);
    const float g2La = c2a * (amL - a2La), g2Lb = c2b * (amL - a2Lb);

    float D1a = 0.f, D1b = 0.f, D2a = 0.f, D2b = 0.f, Ma = 0.f, Mb = 0.f;
    for (int c = 0; c < NC; ++c) {
        const size_t si = (size_t)(c * B_ + b) * H_ + h0;
        f32x2 v;
        v.x = D1a; v.y = D1b; *(f32x2*)&D1[si] = v;
        v.x = D2a; v.y = D2b; *(f32x2*)&D2[si] = v;
        v.x = Ma;  v.y = Mb;  *(f32x2*)&DM[si] = v;
        f32x2 s1 = *(const f32x2*)&Sd1[si];
        f32x2 s2 = *(const f32x2*)&Sd2[si];
        f32x2 sm = *(const f32x2*)&Sm[si];
        float nMa = amL * Ma + D1a * g1La + D2a * g2La + sm.x;
        float nMb = amL * Mb + D1b * g1Lb + D2b * g2Lb + sm.y;
        D1a = a1La * D1a + s1.x;  D1b = a1Lb * D1b + s1.y;
        D2a = a2La * D2a + s2.x;  D2b = a2Lb * D2b + s2.y;
        Ma = nMa;  Mb = nMb;
    }
}

// ---------------- gemm2f: fix-up in A-staging + MFMA + bias + sigmoid --------------------
__global__ __launch_bounds__(256, 3) void gemm2f_kernel(
    const unsigned short* __restrict__ mems, const unsigned short* __restrict__ wob,
    const float* __restrict__ bo,
    const float* __restrict__ G1, const float* __restrict__ G2,
    const float* __restrict__ D1, const float* __restrict__ D2,
    const float* __restrict__ DM, float* __restrict__ out)
{
    __shared__ short As[128 * 64];
    __shared__ short Bs[128 * 64];
    __shared__ float PMl[CLEN];

    const int mt = blockIdx.x;
    const int b = mt >> 3, c0 = (mt & 7) << 3;   // 8 chunks of 16 per 128-row tile
    const int tid = threadIdx.x, l = tid & 63, wv = tid >> 6;
    const int ln = l & 15, qd = l >> 4;
    const int wm = (wv & 1) << 6, wn = (wv >> 1) << 6;

    if (tid < CLEN) {
        float pm = 1.f;
        for (int k = 0; k <= tid; ++k) pm *= 0.8f;
        PMl[tid] = pm;                       // 0.8^{k+1}
    }
    __syncthreads();

    f32x4 acc[4][4] = {};
    const unsigned short* abase = mems + (size_t)(mt * 128) * H_;

    for (int kt = 0; kt < H_; kt += 64) {
        // B tile via async DMA (bf16 wo)
        #pragma unroll
        for (int i = 0; i < 4; ++i) {
            int ch = wv * 4 + i;
            int r  = ch * 8 + (l >> 3);
            int kbl = (l & 7) ^ (r & 7);
            gl_lds16(wob + (size_t)r * H_ + kt + kbl * 8, &Bs[ch * 512 + l * 8]);
        }
        // A staging with fix-up (VALU)
        #pragma unroll
        for (int i = 0; i < 4; ++i) {
            int gi = i * 256 + tid;
            int r = gi >> 3, kbp = gi & 7, kbl = kbp ^ (r & 7);
            int h0 = kt + kbl * 8;
            int k = r & (CLEN - 1), c = c0 + (r >> 4);
            size_t dbase = (size_t)(c * B_ + b) * H_ + h0;
            f32x4 d1a = *(const f32x4*)&D1[dbase], d1b = *(const f32x4*)&D1[dbase + 4];
            f32x4 d2a = *(const f32x4*)&D2[dbase], d2b = *(const f32x4*)&D2[dbase + 4];
            f32x4 dma = *(const f32x4*)&DM[dbase], dmb = *(const f32x4*)&DM[dbase + 4];
            f32x4 g1a = *(const f32x4*)&G1[k * H_ + h0], g1b = *(const f32x4*)&G1[k * H_ + h0 + 4];
            f32x4 g2a = *(const f32x4*)&G2[k * H_ + h0], g2b = *(const f32x4*)&G2[k * H_ + h0 + 4];
            float pm = PMl[k];
            u32x4 mv = *(const u32x4*)(abase + (size_t)r * H_ + h0);
            float v0 = bflo(mv.x) + d1a.x * g1a.x + d2a.x * g2a.x + dma.x * pm;
            float v1 = bfhi(mv.x) + d1a.y * g1a.y + d2a.y * g2a.y + dma.y * pm;
            float v2 = bflo(mv.y) + d1a.z * g1a.z + d2a.z * g2a.z + dma.z * pm;
            float v3 = bfhi(mv.y) + d1a.w * g1a.w + d2a.w * g2a.w + dma.w * pm;
            float v4 = bflo(mv.z) + d1b.x * g1b.x + d2b.x * g2b.x + dmb.x * pm;
            float v5 = bfhi(mv.z) + d1b.y * g1b.y + d2b.y * g2b.y + dmb.y * pm;
            float v6 = bflo(mv.w) + d1b.z * g1b.z + d2b.z * g2b.z + dmb.z * pm;
            float v7 = bfhi(mv.w) + d1b.w * g1b.w + d2b.w * g2b.w + dmb.w * pm;
            u32x4 p;
            p.x = packbf(v0, v1); p.y = packbf(v2, v3);
            p.z = packbf(v4, v5); p.w = packbf(v6, v7);
            *(u32x4*)&As[r * 64 + kbp * 8] = p;
        }
        __syncthreads();
        #pragma unroll
        for (int ks = 0; ks < 64; ks += 32) {
            s16x8 af[4], bfv[4];
            #pragma unroll
            for (int i = 0; i < 4; ++i) {
                int r = wm + i * 16 + ln;
                int kbp = ((ks >> 3) + qd) ^ (r & 7);
                af[i] = *(const s16x8*)&As[r * 64 + kbp * 8];
            }
            #pragma unroll
            for (int j = 0; j < 4; ++j) {
                int r = wn + j * 16 + ln;
                int kbp = ((ks >> 3) + qd) ^ (r & 7);
                bfv[j] = *(const s16x8*)&Bs[r * 64 + kbp * 8];
            }
            #pragma unroll
            for (int i = 0; i < 4; ++i)
                #pragma unroll
                for (int j = 0; j < 4; ++j)
                    acc[i][j] = __builtin_amdgcn_mfma_f32_16x16x32_bf16(
                        af[i], bfv[j], acc[i][j], 0, 0, 0);
        }
        __syncthreads();
    }

    float bov[4];
    #pragma unroll
    for (int j = 0; j < 4; ++j) bov[j] = bo[wn + j * 16 + ln];

    float* orow = out + (size_t)(mt * 128 + wm + qd * 4) * O_ + wn + ln;
    #pragma unroll
    for (int i = 0; i < 4; ++i)
        #pragma unroll
        for (int j = 0; j < 4; ++j)
            #pragma unroll
            for (int r = 0; r < 4; ++r) {
                float v = acc[i][j][r] + bov[j];
                orow[(size_t)(i * 16 + r) * O_ + j * 16] = 1.f / (1.f + __expf(-v));
            }
}

extern "C" void kernel_launch(void* const* d_in, const int* in_sizes, int n_in,
                              void* d_out, int out_size, void* d_ws, size_t ws_size,
                              hipStream_t stream) {
    const float* x    = (const float*)d_in[0];
    const float* w1   = (const float*)d_in[1];
    const float* b1   = (const float*)d_in[2];
    const float* tau1 = (const float*)d_in[3];
    const float* w2   = (const float*)d_in[4];
    const float* b2   = (const float*)d_in[5];
    const float* tau2 = (const float*)d_in[6];
    const float* wo   = (const float*)d_in[7];
    const float* bo   = (const float*)d_in[8];
    float* out = (float*)d_out;

    // ws layout (~177 MiB):
    //  [0,64Mi)        mems bf16 [B*T][H]
    //  [64Mi,128Mi)    xb bf16 [B*T][D]  (written by gemm1f nt=0, read by nt>=1)
    //  [128Mi,176Mi)   Sd1,Sd2,Sm,D1,D2,DM  (NC*B*H f32 = 8 MiB each)
    //  then            G1,G2 (16*512 f32 each), w1b/w2b/wob bf16 contiguous
    char* wsp = (char*)d_ws;
    unsigned int*   mems = (unsigned int*)wsp;
    unsigned short* xb   = (unsigned short*)(wsp + (size_t)64 * 1024 * 1024);
    float* Sd1 = (float*)(wsp + (size_t)128 * 1024 * 1024);
    const size_t SARR = (size_t)NC * B_ * H_;       // 2M floats
    float* Sd2 = Sd1 + SARR;
    float* Sm  = Sd1 + 2 * SARR;
    float* D1  = Sd1 + 3 * SARR;
    float* D2  = Sd1 + 4 * SARR;
    float* DM  = Sd1 + 5 * SARR;
    float* G1  = Sd1 + 6 * SARR;
    float* G2  = G1 + CLEN * H_;
    unsigned short* w1b = (unsigned short*)(G2 + CLEN * H_);
    unsigned short* w2b = w1b + 131072;
    unsigned short* wob = w2b + 131072;

    wcast_kernel<<<dim3(160), 256, 0, stream>>>(w1, w2, wo, (unsigned int*)w1b);
    gtab_kernel<<<dim3(2), 256, 0, stream>>>(tau1, tau2, G1, G2);
    gemm1f_kernel<<<dim3(1024), 256, 0, stream>>>(x, xb, w1b, w2b, b1, tau1, b2, tau2,
                                                  mems, Sd1, Sd2, Sm);
    scanB_kernel<<<dim3(128), 128, 0, stream>>>(Sd1, Sd2, Sm, tau1, tau2, D1, D2, DM);
    gemm2f_kernel<<<dim3(512), 256, 0, stream>>>((const unsigned short*)mems, wob, bo,
                                                 G1, G2, D1, D2, DM, out);
}